// Round 13
// baseline (267.137 us; speedup 1.0000x reference)
//
#include <hip/hip_runtime.h>
#include <stdint.h>

#define NB 8
#define NCLS 19

typedef short s8v __attribute__((ext_vector_type(8)));   // 8 x bf16 (as shorts)
typedef float f4v __attribute__((ext_vector_type(4)));

__device__ __forceinline__ unsigned short f2b(float f){
  union { float f; uint32_t u; } v; v.f = f;
  uint32_t u = v.u;
  uint32_t r = (u + 0x7fffu + ((u >> 16) & 1u)) >> 16;  // RNE f32->bf16
  return (unsigned short)r;
}

// async global->LDS, 16B per lane, wave-uniform LDS base
#define GLOAD16(g, l) __builtin_amdgcn_global_load_lds( \
    (const __attribute__((address_space(1))) unsigned int*)(g), \
    (__attribute__((address_space(3))) unsigned int*)(l), 16, 0, 0)

// ---------------- workspace layout (bytes) ----------------
#define OFF_X512 0
#define OFF_POOL 31490048
#define OFF_Z    32309248   // zbufT bf16 [8][512 o][64 bins] = 512KB
#define OFF_BNS  33128448
#define OFF_BNB  33130496
#define OFF_SEG  33132544
#define OFF_ARGX 35321344   // argxT bf16 [8][19][112][64] swizzled
#define OFF_WSEG 37510144
#define OFF_WF   37805056
// featT (bf16 [8][3712][576], 34.2MB: cols 0-511 feat, 512-575 z-upsample weights)
// lives in out1 scratch (k7 overwrites it last)

// ---------------- K_setup ----------------
__global__ __launch_bounds__(256) void k_setup(
    const float* __restrict__ feat, unsigned short* __restrict__ featT,
    unsigned short* __restrict__ x512p,
    const float* __restrict__ wseg, unsigned short* __restrict__ wsegT,
    const float* __restrict__ wconv, unsigned short* __restrict__ wfT,
    const float* __restrict__ g, const float* __restrict__ be,
    const float* __restrict__ m, const float* __restrict__ v,
    float* __restrict__ sc, float* __restrict__ sh,
    unsigned short* __restrict__ argxT, unsigned short* __restrict__ zbufT,
    float* __restrict__ pooled)
{
  __shared__ unsigned short lt[64*528];
  int bid = blockIdx.x;
  if (bid < 456){                      // ---- ktr: feat f32 -> featT bf16 rows (stride 576)
    int b = bid / 57, px0 = (bid - b*57)*64;
    for (int i = threadIdx.x; i < 64*512; i += 256){
      int c = i >> 6, px = i & 63;
      float val = feat[((size_t)b*512 + c)*3600 + min(px0+px, 3599)];
      lt[px*528 + c] = f2b(val);
    }
    __syncthreads();
    for (int i = threadIdx.x; i < 4096; i += 256){
      int px = i >> 6, c8 = i & 63;
      s8v vv = *(const s8v*)(lt + px*528 + c8*8);
      *(s8v*)(featT + ((size_t)b*3712 + px0 + px)*576 + c8*8) = vv;
    }
    return;
  }
  bid -= 456;
  if (bid < 488){                      // ---- halo ring zero of x512p
    int idx = bid*256 + threadIdx.x;
    if (idx < 124928){
      int pix = idx >> 6;
      int ch  = (idx & 63) << 3;
      int b = pix / 244;
      int r = pix - b*244;
      int h, w;
      if (r < 62){ h = 0; w = r; }
      else if (r < 124){ h = 61; w = r - 62; }
      else if (r < 184){ h = r - 124 + 1; w = 0; }
      else { h = r - 184 + 1; w = 61; }
      s8v z = (s8v){0,0,0,0,0,0,0,0};
      *(s8v*)(x512p + (((size_t)b*62 + h)*62 + w)*512 + ch) = z;
    }
    return;
  }
  bid -= 488;
  if (bid < 576){                      // ---- wsegT: (19,512,3,3) -> bf16 [tap][32][512]
    int idx = bid*256 + threadIdx.x;
    if (idx < 9*32*512){
      int tap = idx / (32*512);
      int rem = idx - tap*(32*512);
      int o = rem >> 9, c = rem & 511;
      float val = (o < NCLS) ? wseg[((size_t)o*512 + c)*9 + tap] : 0.0f;
      wsegT[idx] = f2b(val);
    }
    return;
  }
  bid -= 576;
  if (bid < 1024){                     // ---- wfT: wconv feat-half -> bf16 [o][c]
    int idx = bid*256 + threadIdx.x;
    if (idx < 512*512){
      int o = idx >> 9, c = idx & 511;
      wfT[idx] = f2b(wconv[(size_t)o*1024 + 512 + c]);
    }
    return;
  }
  bid -= 1024;
  if (bid < 2){                        // ---- bn scale/shift
    int i = bid*256 + threadIdx.x;
    if (i < 512){
      float s = g[i] * rsqrtf(v[i] + 1e-5f);
      sc[i] = s; sh[i] = be[i] - m[i]*s;
    }
    return;
  }
  bid -= 2;
  if (bid < 532){                      // ---- zero argxT (pad rows/cols must be 0 each call)
    int gi = bid*256 + threadIdx.x;
    if (gi < 136192){
      s8v z = (s8v){0,0,0,0,0,0,0,0};
      ((s8v*)argxT)[gi] = z;
    }
    return;
  }
  bid -= 532;
  if (bid < 128){                      // ---- zero zbufT (incl. pad bins 50..63)
    int gi = bid*256 + threadIdx.x;
    if (gi < 32768){
      s8v z = (s8v){0,0,0,0,0,0,0,0};
      ((s8v*)zbufT)[gi] = z;
    }
    return;
  }
  bid -= 128;
  if (bid < 116){                      // ---- wext: featT cols 512..575 = per-pixel z-upsample weights
    int row = bid*256 + threadIdx.x;   // 0..29695 = b*3712 + p
    if (row < 29696){
      int b = row / 3712, p = row - b*3712;
      int pc = min(p, 3599);
      int h = pc / 60, w = pc - (pc/60)*60;
      float* wr = (float*)lt + threadIdx.x*64;   // f32 accum (handles duplicate corner bins)
      #pragma unroll
      for (int i = 0; i < 64; i++) wr[i] = 0.f;
      wr[0] = 1.0f;                    // pool=1 branch
      const int pbase[3] = {1,5,14};
      const int psz[3]   = {2,3,6};
      #pragma unroll
      for (int ib = 0; ib < 3; ib++){
        int P = psz[ib];
        float fy = (float)h * (float)(P-1) / 59.0f;
        float fx = (float)w * (float)(P-1) / 59.0f;
        int y0 = (int)fy; int y1 = min(y0+1, P-1); float wy = fy - (float)y0;
        int x0 = (int)fx; int x1 = min(x0+1, P-1); float wx = fx - (float)x0;
        wr[pbase[ib] + y0*P + x0] += (1.f-wy)*(1.f-wx);
        wr[pbase[ib] + y0*P + x1] += (1.f-wy)*wx;
        wr[pbase[ib] + y1*P + x0] += wy*(1.f-wx);
        wr[pbase[ib] + y1*P + x1] += wy*wx;
      }
      unsigned short* dst = featT + ((size_t)b*3712 + p)*576 + 512;
      #pragma unroll
      for (int ch = 0; ch < 8; ch++){
        s8v vv;
        #pragma unroll
        for (int e = 0; e < 8; e++) vv[e] = (short)f2b(wr[ch*8 + e]);
        *(s8v*)(dst + ch*8) = vv;
      }
    }
    return;
  }
  bid -= 116;
  {                                    // ---- k1 pools: 4 bc per block (one per wave)
    int w = threadIdx.x >> 6, lane = threadIdx.x & 63;
    int bc = bid*4 + w;                // 0..4095
    float* rs = (float*)lt + w*64*12;  // alias into lt
    if (lane < 60){
      const float* row = feat + (size_t)bc*3600 + lane*60;
      float s6[6];
      #pragma unroll
      for (int j = 0; j < 6; j++){
        float s = 0.f;
        #pragma unroll
        for (int i = 0; i < 10; i++) s += row[j*10+i];
        s6[j] = s;
      }
      float s3_0 = s6[0]+s6[1], s3_1 = s6[2]+s6[3], s3_2 = s6[4]+s6[5];
      float s2_0 = s3_0 + s6[2], s2_1 = s6[3] + s3_2;
      rs[lane*12+0] = s2_0 + s2_1;
      rs[lane*12+1] = s2_0; rs[lane*12+2] = s2_1;
      rs[lane*12+3] = s3_0; rs[lane*12+4] = s3_1; rs[lane*12+5] = s3_2;
      #pragma unroll
      for (int j = 0; j < 6; j++) rs[lane*12+6+j] = s6[j];
    }
    __syncthreads();
    if (lane < 50){
      int P, by, bx, jcol;
      if (lane == 0){ P=1; by=0; bx=0; jcol=0; }
      else if (lane < 5){ P=2; int l=lane-1; by=l>>1; bx=l&1; jcol=1+bx; }
      else if (lane < 14){ P=3; int l=lane-5; by=l/3; bx=l-(l/3)*3; jcol=3+bx; }
      else { P=6; int l=lane-14; by=l/6; bx=l-(l/6)*6; jcol=6+bx; }
      int k = 60/P;
      float s = 0.f;
      for (int rr = 0; rr < k; rr++) s += rs[(by*k+rr)*12 + jcol];
      pooled[(size_t)bc*50 + lane] = s * (1.0f/((float)k*(float)k));
    }
  }
}

// ---------------- K2: branch 1x1 conv + BN/bias + relu, then zbufT[b][o][bin] = w_conv_branch . y ----------------
__global__ __launch_bounds__(256) void k2_branch(
    const float* __restrict__ pooled, const float* __restrict__ w_psp,
    const float* __restrict__ b_psp0,
    const float* __restrict__ png, const float* __restrict__ pnb,
    const float* __restrict__ pnm, const float* __restrict__ pnv,
    const float* __restrict__ wconv, unsigned short* __restrict__ zbufT)
{
  int bin = blockIdx.x % 50;
  int b   = blockIdx.x / 50;
  int br  = (bin < 1) ? 0 : (bin < 5) ? 1 : (bin < 14) ? 2 : 3;
  __shared__ float pl[512];
  __shared__ float ysh[128];
  int t = threadIdx.x;
  pl[t]       = pooled[((size_t)b*512 + t)*50 + bin];
  pl[t + 256] = pooled[((size_t)b*512 + t + 256)*50 + bin];
  __syncthreads();
  if (t < 128){
    const float* wr = w_psp + ((size_t)br*128 + t)*512;
    float s = 0.f;
    #pragma unroll 8
    for (int c = 0; c < 512; c++) s += pl[c]*wr[c];
    if (br == 0) s += b_psp0[t];
    else {
      int ib = (br-1)*128 + t;
      s = (s - pnm[ib]) * png[ib] * rsqrtf(pnv[ib] + 1e-5f) + pnb[ib];
    }
    ysh[t] = fmaxf(s, 0.f);
  }
  __syncthreads();
  for (int o = t; o < 512; o += 256){
    const float* wc = wconv + (size_t)o*1024 + br*128;
    float s = 0.f;
    #pragma unroll
    for (int c = 0; c < 128; c++) s += ysh[c]*wc[c];
    zbufT[((size_t)b*512 + o)*64 + bin] = f2b(s);
  }
}

// ---------------- K3: GEMM K=576 (feat 512 + z-upsample 64), bf16 MFMA; epilogue = BN+relu only ----------------
__global__ __launch_bounds__(256) void k3_gemm(
    const unsigned short* __restrict__ featT, const unsigned short* __restrict__ wfT,
    const unsigned short* __restrict__ zbufT, const float* __restrict__ bns,
    const float* __restrict__ bnb, unsigned short* __restrict__ x512p)
{
  __shared__ unsigned short lmem[2*128*64];   // A | B
  unsigned short* lA = lmem;
  unsigned short* lB = lmem + 128*64;

  const int t = threadIdx.x;
  const int lane = t & 63;
  const int wave = t >> 6;
  const int wm = wave >> 1;
  const int wn = wave & 1;
  const int pix0 = blockIdx.x * 128;
  const int o0   = blockIdx.y * 128;
  const int b    = blockIdx.z;

  f4v acc[4][4];
  #pragma unroll
  for (int i = 0; i < 4; i++)
    #pragma unroll
    for (int j = 0; j < 4; j++)
      acc[i][j] = (f4v){0.f,0.f,0.f,0.f};

  const int sub  = lane >> 3;
  const int slot = lane & 7;

  for (int kk = 0; kk < 9; kk++){
    #pragma unroll
    for (int j = 0; j < 4; j++){ // A: featT rows (576-wide; kk=8 = weight cols)
      int px = j*32 + wave*8 + sub;
      int pix = min(pix0 + px, 3599);
      const unsigned short* src = featT + ((size_t)b*3712 + pix)*576 + kk*64 + ((slot ^ (px & 7)) << 3);
      GLOAD16(src, lA + j*2048 + wave*512);
    }
    #pragma unroll
    for (int j = 0; j < 4; j++){ // B: wfT rows for kk<8, zbufT rows for kk=8
      int o = j*32 + wave*8 + sub;
      const unsigned short* src = (kk < 8)
        ? wfT + (size_t)(o0 + o)*512 + kk*64 + ((slot ^ (o & 7)) << 3)
        : zbufT + ((size_t)b*512 + o0 + o)*64 + ((slot ^ (o & 7)) << 3);
      GLOAD16(src, lB + j*2048 + wave*512);
    }
    __syncthreads();
    #pragma unroll
    for (int ks = 0; ks < 2; ks++){
      const int chunk = ks*4 + (lane >> 4);
      s8v af[4], bg[4];
      #pragma unroll
      for (int mf = 0; mf < 4; mf++){
        int p = wm*64 + mf*16 + (lane & 15);
        af[mf] = *(s8v*)((char*)lA + p*128 + ((chunk ^ (p & 7)))*16);
      }
      #pragma unroll
      for (int nf = 0; nf < 4; nf++){
        int o = wn*64 + nf*16 + (lane & 15);
        bg[nf] = *(s8v*)((char*)lB + o*128 + ((chunk ^ (o & 7)))*16);
      }
      #pragma unroll
      for (int mf = 0; mf < 4; mf++)
        #pragma unroll
        for (int nf = 0; nf < 4; nf++)
          acc[mf][nf] = __builtin_amdgcn_mfma_f32_16x16x32_bf16(af[mf], bg[nf], acc[mf][nf], 0, 0, 0);
    }
    __syncthreads();
  }

  // epilogue: BN + relu -> bf16 NHWC (halo'd)
  float* lsc = (float*)lmem;
  float* lsh = lsc + 128;
  if (t < 128){ lsc[t] = bns[o0 + t]; lsh[t] = bnb[o0 + t]; }
  __syncthreads();

  #pragma unroll
  for (int mf = 0; mf < 4; mf++){
    #pragma unroll
    for (int r = 0; r < 4; r++){
      int p = pix0 + wm*64 + mf*16 + (lane >> 4)*4 + r;
      if (p >= 3600) continue;
      int h = p / 60, w = p - (p/60)*60;
      size_t obase = (((size_t)b*62 + (h+1))*62 + (w+1))*512 + o0;
      #pragma unroll
      for (int nf = 0; nf < 4; nf++){
        int ol = wn*64 + nf*16 + (lane & 15);
        float v = fmaxf(acc[mf][nf][r] * lsc[ol] + lsh[ol], 0.f);
        x512p[obase + ol] = f2b(v);
      }
    }
  }
}

// ---------------- K4v2: 3x3 conv, 512 threads / 8 waves (g=px-group, nh=o-half) ----------------
__global__ __launch_bounds__(512) void k4_conv(
    const unsigned short* __restrict__ x512p, const unsigned short* __restrict__ wsegT,
    const float* __restrict__ bseg, float* __restrict__ seg60)
{
  __shared__ unsigned short lW[32*512];       // [o][c] bf16 swizzled, rows 1024B
  const int h = blockIdx.x;
  const int b = blockIdx.y;
  const int t = threadIdx.x;
  const int lane = t & 63;
  const int wave = t >> 6;                    // 0..7
  const int g  = wave & 3;                    // px group
  const int nh = wave >> 2;                   // o half
  const int wpix = g*16 + (lane & 15);
  const int wld = min(wpix, 59);

  f4v acc = (f4v){0.f,0.f,0.f,0.f};

  for (int tap = 0; tap < 9; tap++){
    __syncthreads();
    for (int i = t; i < 2048; i += 512){
      int orow = i >> 6;
      int cn = i & 63;
      s8v v = *(const s8v*)(wsegT + ((size_t)tap*32 + orow)*512 + cn*8);
      *(s8v*)((char*)lW + orow*1024 + ((cn ^ (orow & 7)))*16) = v;
    }
    __syncthreads();
    int dy = tap/3 - 1, dx = tap - (tap/3)*3 - 1;
    const unsigned short* arow = x512p + (((size_t)b*62 + (h+dy+1))*62 + (wld+dx+1))*512 + (lane>>4)*8;
    #pragma unroll 4
    for (int cs = 0; cs < 16; cs++){
      int cb = cs*32;
      s8v a = *(const s8v*)(arow + cb);
      int o = nh*16 + (lane & 15);
      int chunk = (cb >> 3) + (lane >> 4);
      s8v bv = *(s8v*)((char*)lW + o*1024 + ((chunk ^ (o & 7)))*16);
      acc = __builtin_amdgcn_mfma_f32_16x16x32_bf16(a, bv, acc, 0, 0, 0);
    }
  }
  {
    int o = nh*16 + (lane & 15);
    if (o < NCLS){
      float bias = bseg[o];
      #pragma unroll
      for (int r = 0; r < 4; r++){
        int wst = g*16 + (lane >> 4)*4 + r;
        if (wst < 60)
          seg60[(((size_t)b*60 + h)*60 + wst)*NCLS + o] = acc[r] + bias;
      }
    }
  }
}

// ---------------- K5v3: LDS-staged bilinear 480 + argmax, 512 threads / 8 waves ----------------
__global__ __launch_bounds__(512) void k5_argmax(const float* __restrict__ seg60, unsigned short* __restrict__ argxT){
  int fy = blockIdx.x, b = blockIdx.y;
  __shared__ float L[3*60*20];                 // [row][x][c pad20], col19 = -3e38
  int ylo;
  { float yy0 = (float)(fy*8) * (59.0f/479.0f); ylo = (int)yy0; }
  for (int i = threadIdx.x; i < 3600; i += 512){
    int r = i/1200, rem = i - r*1200, x = rem/20, c = rem - x*20;
    int row = min(ylo + r, 59);
    L[i] = (c < 19) ? seg60[(((size_t)b*60 + row)*60 + x)*NCLS + c] : -3.0e38f;
  }
  __syncthreads();
  int wave = threadIdx.x >> 6, lane = threadIdx.x & 63;
  int py = fy*8 + (lane >> 3), lpx = lane & 7;
  float yy = (float)py * (59.0f/479.0f); int y0 = (int)yy; int y1 = min(y0+1, 59); float wy = yy - (float)y0;
  const float* r0 = L + (y0 - ylo)*1200;
  const float* r1 = L + (y1 - ylo)*1200;
  #pragma unroll 2
  for (int pass = 0; pass < 8; pass++){
    int fx = pass*8 + wave;                    // 0..63, guard below
    if (fx >= 60) continue;
    int px = fx*8 + lpx;
    float xx = (float)px * (59.0f/479.0f); int x0 = (int)xx; int x1 = min(x0+1, 59); float wx = xx - (float)x0;
    float w00 = (1.f-wy)*(1.f-wx), w01 = (1.f-wy)*wx, w10 = wy*(1.f-wx), w11 = wy*wx;
    const float* s00 = r0 + x0*20; const float* s01 = r0 + x1*20;
    const float* s10 = r1 + x0*20; const float* s11 = r1 + x1*20;
    float best = -3.0e38f; int bc = 0;
    #pragma unroll
    for (int c = 0; c < NCLS; c++){
      float v = w00*s00[c] + w01*s01[c] + w10*s10[c] + w11*s11[c];
      if (v > best){ best = v; bc = c; }       // strict > == first-occurrence argmax
    }
    int cnt = 0;
    #pragma unroll
    for (int c = 0; c < NCLS; c++){
      unsigned long long m = __ballot(bc == c);
      if (lane == c) cnt = __popcll(m);
    }
    int ky = fy/10, qy = fy - (fy/10)*10, kx = fx/10, qx = fx - (fx/10)*10;
    int q = qy*10 + qx, k = ky*6 + kx;         // wave-uniform
    if (lane < NCLS){
      unsigned short hv = f2b((float)cnt * (1.0f/64.0f));   // k/64: bf16-exact
      argxT[(size_t)(b*NCLS + lane)*7168 + q*64 + (((k>>3) ^ (q&7))<<3) + (k&7)] = hv;
    }
  }
}

// ---------------- K7v5: MFMA corr + reg h-table + fused out2 copy ----------------
__global__ __launch_bounds__(256) void k7_final(
    const float* __restrict__ att, const unsigned short* __restrict__ argxT,
    const float* __restrict__ seg60, float* __restrict__ out, float* __restrict__ out2)
{
  int pr = blockIdx.x, c = blockIdx.y, b = blockIdx.z;
  __shared__ char pool[22720];
  unsigned short* Abf = (unsigned short*)pool;            // [48][64] swz (phase A)
  unsigned short* Ubf = (unsigned short*)(pool + 6144);   // [112][64] swz (phase A)
  float* corrl = (float*)pool;                            // [48][112] (phase B, overlaps A/U)
  float* inv   = (float*)(pool + 21504);                  // [48]
  float* srow  = (float*)(pool + 21696);                  // [4][64]
  const int t = threadIdx.x;
  const int lane = t & 63;
  const int wave = t >> 6;

  int ybase; { float yy0 = (float)(pr*10)*(59.0f/479.0f); ybase = (int)yy0; }

  // ---- phase 1: stage A (att->bf16 swizzled) + write out2 copy, U via GLOAD16, srow, inv ----
  const size_t aoff = (((size_t)b*NCLS + c)*2304 + (size_t)pr*48)*36;
  const float* ab = att + aoff;
  float* o2 = out2 + aoff;
  for (int i = t; i < 768; i += 256){
    int pc = i >> 4, j = i & 15;          // j: 4-k slot (0..15), data for j<9
    ushort4 w4 = make_ushort4(0,0,0,0);
    if (j < 9){
      f4v v = *(const f4v*)(ab + pc*36 + j*4);
      *(f4v*)(o2 + pc*36 + j*4) = v;      // fused attentions -> out2 copy
      w4.x = f2b(v[0]); w4.y = f2b(v[1]); w4.z = f2b(v[2]); w4.w = f2b(v[3]);
    }
    int ch = j >> 1;
    *(ushort4*)((char*)Abf + pc*128 + (((ch ^ (pc & 7)))<<4) + (j & 1)*8) = w4;
  }
  {
    const unsigned short* up = argxT + (size_t)(b*NCLS + c)*7168;
    #pragma unroll
    for (int r = 0; r < 4; r++){
      int chunk0 = r*256 + wave*64;
      if (chunk0 < 896)                   // wave-uniform
        GLOAD16(up + (size_t)(chunk0 + lane)*8, Ubf + (size_t)chunk0*8);
    }
  }
  if (t < 240){
    int j = t/60, x = t - (t/60)*60;
    int row = min(ybase + j, 59);
    srow[j*64 + x] = seg60[(((size_t)b*60 + row)*60 + x)*NCLS + c];
  }
  if (t < 48){
    int nz = 0;
    #pragma unroll
    for (int j2 = 0; j2 < 9; j2++){
      f4v v = *(const f4v*)(ab + t*36 + j2*4);
      nz += (v[0]!=0.f)+(v[1]!=0.f)+(v[2]!=0.f)+(v[3]!=0.f);
    }
    inv[t] = 1.0f/((float)nz + 1e-5f);
  }
  __syncthreads();

  // ---- phase 2: MFMA (21 tile-pairs over 4 waves) + h-table into registers ----
  f4v acc[6];
  #pragma unroll
  for (int s = 0; s < 6; s++) acc[s] = (f4v){0.f,0.f,0.f,0.f};
  #pragma unroll
  for (int s = 0; s < 6; s++){
    int pi = wave + s*4;
    if (pi < 21){
      int M = pi/7, N = pi - (pi/7)*7;
      #pragma unroll
      for (int ks = 0; ks < 2; ks++){
        int chunk = ks*4 + (lane >> 4);
        int ar = M*16 + (lane & 15);
        s8v af = *(s8v*)((char*)Abf + ar*128 + ((chunk ^ (ar & 7))<<4));
        int qr = N*16 + (lane & 15);
        s8v bg = *(s8v*)((char*)Ubf + qr*128 + ((chunk ^ (qr & 7))<<4));
        acc[s] = __builtin_amdgcn_mfma_f32_16x16x32_bf16(af, bg, acc[s], 0, 0, 0);
      }
    }
  }
  float hA[4], hB[4];
  {
    float xxa = (float)t * (59.0f/479.0f);
    int xa0 = (int)xxa; int xa1 = min(xa0+1, 59); float wxa = xxa - (float)xa0;
    int px2 = t + 256;
    float xxb = (float)px2 * (59.0f/479.0f);
    int xb0 = (int)xxb; int xb1 = min(xb0+1, 59); float wxb = xxb - (float)xb0;
    #pragma unroll
    for (int j = 0; j < 4; j++){
      hA[j] = (1.f-wxa)*srow[j*64 + xa0] + wxa*srow[j*64 + xa1];
      hB[j] = (px2 < 480) ? ((1.f-wxb)*srow[j*64 + xb0] + wxb*srow[j*64 + xb1]) : 0.f;
    }
  }
  __syncthreads();

  // ---- phase 3: corr = acc*inv -> corrl (overwrites A/U) ----
  #pragma unroll
  for (int s = 0; s < 6; s++){
    int pi = wave + s*4;
    if (pi < 21){
      int M = pi/7, N = pi - (pi/7)*7;
      int q = N*16 + (lane & 15);
      #pragma unroll
      for (int r = 0; r < 4; r++){
        int pc = M*16 + (lane >> 4)*4 + r;
        corrl[pc*112 + q] = acc[s][r] * inv[pc];
      }
    }
  }
  __syncthreads();

  // ---- phase 4: coalesced output, h from registers (row-select is wave-uniform) ----
  float* outb = out + ((size_t)b*NCLS + c)*230400 + (size_t)pr*4800;
  int pcA = (t*6554) >> 16, qxA = t - pcA*10;
  int px2 = t + 256;
  int pcB = (px2*6554) >> 16, qxB = px2 - pcB*10;
  #pragma unroll
  for (int qy = 0; qy < 10; qy++){
    int py = pr*10 + qy;
    float yy = (float)py * (59.0f/479.0f);
    int y0 = (int)yy; int y1 = min(y0+1, 59); float wy = yy - (float)y0;
    int j0 = y0 - ybase, j1 = y1 - ybase;      // uniform across block
    float h0a = (j0==0)?hA[0]:(j0==1)?hA[1]:(j0==2)?hA[2]:hA[3];
    float h1a = (j1==0)?hA[0]:(j1==1)?hA[1]:(j1==2)?hA[2]:hA[3];
    float omw = 1.f - wy;
    float xv = omw*h0a + wy*h1a;
    outb[qy*480 + t] = xv * (1.f + corrl[pcA*112 + qy*10 + qxA]);
    if (px2 < 480){
      float h0b = (j0==0)?hB[0]:(j0==1)?hB[1]:(j0==2)?hB[2]:hB[3];
      float h1b = (j1==0)?hB[0]:(j1==1)?hB[1]:(j1==2)?hB[2]:hB[3];
      float xv2 = omw*h0b + wy*h1b;
      outb[qy*480 + px2] = xv2 * (1.f + corrl[pcB*112 + qy*10 + qxB]);
    }
  }
}

extern "C" void kernel_launch(void* const* d_in, const int* in_sizes, int n_in,
                              void* d_out, int out_size, void* d_ws, size_t ws_size,
                              hipStream_t stream)
{
  (void)in_sizes; (void)n_in; (void)out_size; (void)ws_size;
  const float* feat   = (const float*)d_in[0];
  const float* attn   = (const float*)d_in[1];
  const float* w_psp  = (const float*)d_in[2];
  const float* b_psp0 = (const float*)d_in[3];
  const float* png    = (const float*)d_in[4];
  const float* pnb    = (const float*)d_in[5];
  const float* pnm    = (const float*)d_in[6];
  const float* pnv    = (const float*)d_in[7];
  const float* wconv  = (const float*)d_in[8];
  const float* cg     = (const float*)d_in[9];
  const float* cbt    = (const float*)d_in[10];
  const float* cm     = (const float*)d_in[11];
  const float* cv     = (const float*)d_in[12];
  const float* wseg   = (const float*)d_in[13];
  const float* bseg   = (const float*)d_in[14];

  float* out1 = (float*)d_out;                       // [8,19,480,480]
  float* out2 = out1 + (size_t)35020800;             // attentions copy

  char* ws = (char*)d_ws;
  unsigned short* x512p = (unsigned short*)(ws + OFF_X512);
  float* pooled = (float*)(ws + OFF_POOL);
  unsigned short* zbufT = (unsigned short*)(ws + OFF_Z);
  float* bns    = (float*)(ws + OFF_BNS);
  float* bnb    = (float*)(ws + OFF_BNB);
  float* seg60  = (float*)(ws + OFF_SEG);
  unsigned short* argxT = (unsigned short*)(ws + OFF_ARGX);
  unsigned short* wsegT = (unsigned short*)(ws + OFF_WSEG);
  unsigned short* wfT   = (unsigned short*)(ws + OFF_WF);
  unsigned short* featT = (unsigned short*)d_out;    // scratch inside out1 (k7 overwrites)

  k_setup<<<4346, 256, 0, stream>>>(feat, featT, x512p, wseg, wsegT, wconv, wfT,
                                    cg, cbt, cm, cv, bns, bnb, argxT, zbufT, pooled);
  k2_branch<<<400, 256, 0, stream>>>(pooled, w_psp, b_psp0, png, pnb, pnm, pnv, wconv, zbufT);
  k3_gemm<<<dim3(29,4,8), 256, 0, stream>>>(featT, wfT, zbufT, bns, bnb, x512p);
  k4_conv<<<dim3(60,8), 512, 0, stream>>>(x512p, wsegT, bseg, seg60);
  k5_argmax<<<dim3(60,8), 512, 0, stream>>>(seg60, argxT);
  k7_final<<<dim3(48,19,8), 256, 0, stream>>>(attn, argxT, seg60, out1, out2);
}

// Round 14
// 245.325 us; speedup vs baseline: 1.0889x; 1.0889x over previous
//
#include <hip/hip_runtime.h>
#include <stdint.h>

#define NB 8
#define NCLS 19

typedef short s8v __attribute__((ext_vector_type(8)));   // 8 x bf16 (as shorts)
typedef float f4v __attribute__((ext_vector_type(4)));

__device__ __forceinline__ unsigned short f2b(float f){
  union { float f; uint32_t u; } v; v.f = f;
  uint32_t u = v.u;
  uint32_t r = (u + 0x7fffu + ((u >> 16) & 1u)) >> 16;  // RNE f32->bf16
  return (unsigned short)r;
}

// async global->LDS, 16B per lane, wave-uniform LDS base
#define GLOAD16(g, l) __builtin_amdgcn_global_load_lds( \
    (const __attribute__((address_space(1))) unsigned int*)(g), \
    (__attribute__((address_space(3))) unsigned int*)(l), 16, 0, 0)

// ---------------- workspace layout (bytes) ----------------
#define OFF_X512 0
#define OFF_POOL 31490048
#define OFF_Z    32309248   // zbufT bf16 [8][512 o][64 bins] = 512KB
#define OFF_BNS  33128448
#define OFF_BNB  33130496
#define OFF_SEG  33132544
#define OFF_ARGX 35321344   // argxT bf16 [8][19][112][64] swizzled
#define OFF_WSEG 37510144
#define OFF_WF   37805056
// featT (bf16 [8][3712][576], 34.2MB: cols 0-511 feat, 512-575 z-upsample weights)
// lives in out1 scratch (k7 overwrites it last)

// ---------------- K_setup ----------------
__global__ __launch_bounds__(256) void k_setup(
    const float* __restrict__ feat, unsigned short* __restrict__ featT,
    unsigned short* __restrict__ x512p,
    const float* __restrict__ wseg, unsigned short* __restrict__ wsegT,
    const float* __restrict__ wconv, unsigned short* __restrict__ wfT,
    const float* __restrict__ g, const float* __restrict__ be,
    const float* __restrict__ m, const float* __restrict__ v,
    float* __restrict__ sc, float* __restrict__ sh,
    unsigned short* __restrict__ argxT, unsigned short* __restrict__ zbufT,
    float* __restrict__ pooled)
{
  __shared__ unsigned short lt[64*528];
  int bid = blockIdx.x;
  if (bid < 456){                      // ---- ktr: feat f32 -> featT bf16 rows (stride 576)
    int b = bid / 57, px0 = (bid - b*57)*64;
    for (int i = threadIdx.x; i < 64*512; i += 256){
      int c = i >> 6, px = i & 63;
      float val = feat[((size_t)b*512 + c)*3600 + min(px0+px, 3599)];
      lt[px*528 + c] = f2b(val);
    }
    __syncthreads();
    for (int i = threadIdx.x; i < 4096; i += 256){
      int px = i >> 6, c8 = i & 63;
      s8v vv = *(const s8v*)(lt + px*528 + c8*8);
      *(s8v*)(featT + ((size_t)b*3712 + px0 + px)*576 + c8*8) = vv;
    }
    return;
  }
  bid -= 456;
  if (bid < 488){                      // ---- halo ring zero of x512p
    int idx = bid*256 + threadIdx.x;
    if (idx < 124928){
      int pix = idx >> 6;
      int ch  = (idx & 63) << 3;
      int b = pix / 244;
      int r = pix - b*244;
      int h, w;
      if (r < 62){ h = 0; w = r; }
      else if (r < 124){ h = 61; w = r - 62; }
      else if (r < 184){ h = r - 124 + 1; w = 0; }
      else { h = r - 184 + 1; w = 61; }
      s8v z = (s8v){0,0,0,0,0,0,0,0};
      *(s8v*)(x512p + (((size_t)b*62 + h)*62 + w)*512 + ch) = z;
    }
    return;
  }
  bid -= 488;
  if (bid < 576){                      // ---- wsegT: (19,512,3,3) -> bf16 [tap][32][512]
    int idx = bid*256 + threadIdx.x;
    if (idx < 9*32*512){
      int tap = idx / (32*512);
      int rem = idx - tap*(32*512);
      int o = rem >> 9, c = rem & 511;
      float val = (o < NCLS) ? wseg[((size_t)o*512 + c)*9 + tap] : 0.0f;
      wsegT[idx] = f2b(val);
    }
    return;
  }
  bid -= 576;
  if (bid < 1024){                     // ---- wfT: wconv feat-half -> bf16 [o][c]
    int idx = bid*256 + threadIdx.x;
    if (idx < 512*512){
      int o = idx >> 9, c = idx & 511;
      wfT[idx] = f2b(wconv[(size_t)o*1024 + 512 + c]);
    }
    return;
  }
  bid -= 1024;
  if (bid < 2){                        // ---- bn scale/shift
    int i = bid*256 + threadIdx.x;
    if (i < 512){
      float s = g[i] * rsqrtf(v[i] + 1e-5f);
      sc[i] = s; sh[i] = be[i] - m[i]*s;
    }
    return;
  }
  bid -= 2;
  if (bid < 532){                      // ---- zero argxT (pad rows/cols must be 0 each call)
    int gi = bid*256 + threadIdx.x;
    if (gi < 136192){
      s8v z = (s8v){0,0,0,0,0,0,0,0};
      ((s8v*)argxT)[gi] = z;
    }
    return;
  }
  bid -= 532;
  if (bid < 128){                      // ---- zero zbufT (incl. pad bins 50..63)
    int gi = bid*256 + threadIdx.x;
    if (gi < 32768){
      s8v z = (s8v){0,0,0,0,0,0,0,0};
      ((s8v*)zbufT)[gi] = z;
    }
    return;
  }
  bid -= 128;
  if (bid < 116){                      // ---- wext: featT cols 512..575 = per-pixel z-upsample weights
    int row = bid*256 + threadIdx.x;   // 0..29695 = b*3712 + p
    if (row < 29696){
      int b = row / 3712, p = row - b*3712;
      int pc = min(p, 3599);
      int h = pc / 60, w = pc - (pc/60)*60;
      float* wr = (float*)lt + threadIdx.x*64;   // f32 accum (handles duplicate corner bins)
      #pragma unroll
      for (int i = 0; i < 64; i++) wr[i] = 0.f;
      wr[0] = 1.0f;                    // pool=1 branch
      const int pbase[3] = {1,5,14};
      const int psz[3]   = {2,3,6};
      #pragma unroll
      for (int ib = 0; ib < 3; ib++){
        int P = psz[ib];
        float fy = (float)h * (float)(P-1) / 59.0f;
        float fx = (float)w * (float)(P-1) / 59.0f;
        int y0 = (int)fy; int y1 = min(y0+1, P-1); float wy = fy - (float)y0;
        int x0 = (int)fx; int x1 = min(x0+1, P-1); float wx = fx - (float)x0;
        wr[pbase[ib] + y0*P + x0] += (1.f-wy)*(1.f-wx);
        wr[pbase[ib] + y0*P + x1] += (1.f-wy)*wx;
        wr[pbase[ib] + y1*P + x0] += wy*(1.f-wx);
        wr[pbase[ib] + y1*P + x1] += wy*wx;
      }
      unsigned short* dst = featT + ((size_t)b*3712 + p)*576 + 512;
      #pragma unroll
      for (int ch = 0; ch < 8; ch++){
        s8v vv;
        #pragma unroll
        for (int e = 0; e < 8; e++) vv[e] = (short)f2b(wr[ch*8 + e]);
        *(s8v*)(dst + ch*8) = vv;
      }
    }
    return;
  }
  bid -= 116;
  {                                    // ---- k1 pools: 4 bc per block (one per wave)
    int w = threadIdx.x >> 6, lane = threadIdx.x & 63;
    int bc = bid*4 + w;                // 0..4095
    float* rs = (float*)lt + w*64*12;  // alias into lt
    if (lane < 60){
      const float* row = feat + (size_t)bc*3600 + lane*60;
      float s6[6];
      #pragma unroll
      for (int j = 0; j < 6; j++){
        float s = 0.f;
        #pragma unroll
        for (int i = 0; i < 10; i++) s += row[j*10+i];
        s6[j] = s;
      }
      float s3_0 = s6[0]+s6[1], s3_1 = s6[2]+s6[3], s3_2 = s6[4]+s6[5];
      float s2_0 = s3_0 + s6[2], s2_1 = s6[3] + s3_2;
      rs[lane*12+0] = s2_0 + s2_1;
      rs[lane*12+1] = s2_0; rs[lane*12+2] = s2_1;
      rs[lane*12+3] = s3_0; rs[lane*12+4] = s3_1; rs[lane*12+5] = s3_2;
      #pragma unroll
      for (int j = 0; j < 6; j++) rs[lane*12+6+j] = s6[j];
    }
    __syncthreads();
    if (lane < 50){
      int P, by, bx, jcol;
      if (lane == 0){ P=1; by=0; bx=0; jcol=0; }
      else if (lane < 5){ P=2; int l=lane-1; by=l>>1; bx=l&1; jcol=1+bx; }
      else if (lane < 14){ P=3; int l=lane-5; by=l/3; bx=l-(l/3)*3; jcol=3+bx; }
      else { P=6; int l=lane-14; by=l/6; bx=l-(l/6)*6; jcol=6+bx; }
      int k = 60/P;
      float s = 0.f;
      for (int rr = 0; rr < k; rr++) s += rs[(by*k+rr)*12 + jcol];
      pooled[(size_t)bc*50 + lane] = s * (1.0f/((float)k*(float)k));
    }
  }
}

// ---------------- K2: branch 1x1 conv + BN/bias + relu, then zbufT[b][o][bin] = w_conv_branch . y ----------------
__global__ __launch_bounds__(256) void k2_branch(
    const float* __restrict__ pooled, const float* __restrict__ w_psp,
    const float* __restrict__ b_psp0,
    const float* __restrict__ png, const float* __restrict__ pnb,
    const float* __restrict__ pnm, const float* __restrict__ pnv,
    const float* __restrict__ wconv, unsigned short* __restrict__ zbufT)
{
  int bin = blockIdx.x % 50;
  int b   = blockIdx.x / 50;
  int br  = (bin < 1) ? 0 : (bin < 5) ? 1 : (bin < 14) ? 2 : 3;
  __shared__ float pl[512];
  __shared__ float ysh[128];
  int t = threadIdx.x;
  pl[t]       = pooled[((size_t)b*512 + t)*50 + bin];
  pl[t + 256] = pooled[((size_t)b*512 + t + 256)*50 + bin];
  __syncthreads();
  if (t < 128){
    const float* wr = w_psp + ((size_t)br*128 + t)*512;
    float s = 0.f;
    #pragma unroll 8
    for (int c = 0; c < 512; c++) s += pl[c]*wr[c];
    if (br == 0) s += b_psp0[t];
    else {
      int ib = (br-1)*128 + t;
      s = (s - pnm[ib]) * png[ib] * rsqrtf(pnv[ib] + 1e-5f) + pnb[ib];
    }
    ysh[t] = fmaxf(s, 0.f);
  }
  __syncthreads();
  for (int o = t; o < 512; o += 256){
    const float* wc = wconv + (size_t)o*1024 + br*128;
    float s = 0.f;
    #pragma unroll
    for (int c = 0; c < 128; c++) s += ysh[c]*wc[c];
    zbufT[((size_t)b*512 + o)*64 + bin] = f2b(s);
  }
}

// ---------------- K3: GEMM K=576, bf16 MFMA; grid (o,pix,b) so A-panel sharers are dispatch-adjacent ----------------
__global__ __launch_bounds__(256) void k3_gemm(
    const unsigned short* __restrict__ featT, const unsigned short* __restrict__ wfT,
    const unsigned short* __restrict__ zbufT, const float* __restrict__ bns,
    const float* __restrict__ bnb, unsigned short* __restrict__ x512p)
{
  __shared__ unsigned short lmem[2*128*64];   // A | B
  unsigned short* lA = lmem;
  unsigned short* lB = lmem + 128*64;

  const int t = threadIdx.x;
  const int lane = t & 63;
  const int wave = t >> 6;
  const int wm = wave >> 1;
  const int wn = wave & 1;
  const int pix0 = blockIdx.y * 128;   // swapped: y = pixel tile
  const int o0   = blockIdx.x * 128;   // x fastest -> 4 o-tiles sharing A-panel adjacent
  const int b    = blockIdx.z;

  f4v acc[4][4];
  #pragma unroll
  for (int i = 0; i < 4; i++)
    #pragma unroll
    for (int j = 0; j < 4; j++)
      acc[i][j] = (f4v){0.f,0.f,0.f,0.f};

  const int sub  = lane >> 3;
  const int slot = lane & 7;

  for (int kk = 0; kk < 9; kk++){
    #pragma unroll
    for (int j = 0; j < 4; j++){ // A: featT rows (576-wide; kk=8 = weight cols)
      int px = j*32 + wave*8 + sub;
      int pix = min(pix0 + px, 3599);
      const unsigned short* src = featT + ((size_t)b*3712 + pix)*576 + kk*64 + ((slot ^ (px & 7)) << 3);
      GLOAD16(src, lA + j*2048 + wave*512);
    }
    #pragma unroll
    for (int j = 0; j < 4; j++){ // B: wfT rows for kk<8, zbufT rows for kk=8
      int o = j*32 + wave*8 + sub;
      const unsigned short* src = (kk < 8)
        ? wfT + (size_t)(o0 + o)*512 + kk*64 + ((slot ^ (o & 7)) << 3)
        : zbufT + ((size_t)b*512 + o0 + o)*64 + ((slot ^ (o & 7)) << 3);
      GLOAD16(src, lB + j*2048 + wave*512);
    }
    __syncthreads();
    #pragma unroll
    for (int ks = 0; ks < 2; ks++){
      const int chunk = ks*4 + (lane >> 4);
      s8v af[4], bg[4];
      #pragma unroll
      for (int mf = 0; mf < 4; mf++){
        int p = wm*64 + mf*16 + (lane & 15);
        af[mf] = *(s8v*)((char*)lA + p*128 + ((chunk ^ (p & 7)))*16);
      }
      #pragma unroll
      for (int nf = 0; nf < 4; nf++){
        int o = wn*64 + nf*16 + (lane & 15);
        bg[nf] = *(s8v*)((char*)lB + o*128 + ((chunk ^ (o & 7)))*16);
      }
      #pragma unroll
      for (int mf = 0; mf < 4; mf++)
        #pragma unroll
        for (int nf = 0; nf < 4; nf++)
          acc[mf][nf] = __builtin_amdgcn_mfma_f32_16x16x32_bf16(af[mf], bg[nf], acc[mf][nf], 0, 0, 0);
    }
    __syncthreads();
  }

  // epilogue: BN + relu -> bf16 NHWC (halo'd)
  float* lsc = (float*)lmem;
  float* lsh = lsc + 128;
  if (t < 128){ lsc[t] = bns[o0 + t]; lsh[t] = bnb[o0 + t]; }
  __syncthreads();

  #pragma unroll
  for (int mf = 0; mf < 4; mf++){
    #pragma unroll
    for (int r = 0; r < 4; r++){
      int p = pix0 + wm*64 + mf*16 + (lane >> 4)*4 + r;
      if (p >= 3600) continue;
      int h = p / 60, w = p - (p/60)*60;
      size_t obase = (((size_t)b*62 + (h+1))*62 + (w+1))*512 + o0;
      #pragma unroll
      for (int nf = 0; nf < 4; nf++){
        int ol = wn*64 + nf*16 + (lane & 15);
        float v = fmaxf(acc[mf][nf][r] * lsc[ol] + lsh[ol], 0.f);
        x512p[obase + ol] = f2b(v);
      }
    }
  }
}

// ---------------- K4: 3x3 conv (SAME) via implicit GEMM, 19->pad32 out ch (R12 version) ----------------
__global__ __launch_bounds__(256) void k4_conv(
    const unsigned short* __restrict__ x512p, const unsigned short* __restrict__ wsegT,
    const float* __restrict__ bseg, float* __restrict__ seg60)
{
  __shared__ unsigned short lW[32*512];       // [o][c] bf16 swizzled, rows 1024B
  const int h = blockIdx.x;
  const int b = blockIdx.y;
  const int t = threadIdx.x;
  const int lane = t & 63;
  const int wave = t >> 6;
  const int wpix = wave*16 + (lane & 15);     // A-supply column (w coord)
  const int wld = min(wpix, 59);

  f4v acc[2];
  acc[0] = (f4v){0.f,0.f,0.f,0.f};
  acc[1] = (f4v){0.f,0.f,0.f,0.f};

  for (int tap = 0; tap < 9; tap++){
    __syncthreads();
    for (int i = t; i < 2048; i += 256){
      int orow = i >> 6;
      int cn = i & 63;
      s8v v = *(const s8v*)(wsegT + ((size_t)tap*32 + orow)*512 + cn*8);
      *(s8v*)((char*)lW + orow*1024 + ((cn ^ (orow & 7)))*16) = v;
    }
    __syncthreads();
    int dy = tap/3 - 1, dx = tap - (tap/3)*3 - 1;
    const unsigned short* arow = x512p + (((size_t)b*62 + (h+dy+1))*62 + (wld+dx+1))*512 + (lane>>4)*8;
    #pragma unroll 4
    for (int cs = 0; cs < 16; cs++){
      int cb = cs*32;
      s8v a = *(const s8v*)(arow + cb);
      #pragma unroll
      for (int nf = 0; nf < 2; nf++){
        int o = nf*16 + (lane & 15);
        int chunk = (cb >> 3) + (lane >> 4);
        s8v bv = *(s8v*)((char*)lW + o*1024 + ((chunk ^ (o & 7)))*16);
        acc[nf] = __builtin_amdgcn_mfma_f32_16x16x32_bf16(a, bv, acc[nf], 0, 0, 0);
      }
    }
  }
  #pragma unroll
  for (int nf = 0; nf < 2; nf++){
    int o = nf*16 + (lane & 15);
    if (o < NCLS){
      float bias = bseg[o];
      #pragma unroll
      for (int r = 0; r < 4; r++){
        int wst = wave*16 + (lane >> 4)*4 + r;
        if (wst < 60)
          seg60[(((size_t)b*60 + h)*60 + wst)*NCLS + o] = acc[nf][r] + bias;
      }
    }
  }
}

// ---------------- K5v2: LDS-staged bilinear 480 + argmax + 8x8 one-hot mean (R12 version) ----------------
__global__ __launch_bounds__(256) void k5_argmax(const float* __restrict__ seg60, unsigned short* __restrict__ argxT){
  int fy = blockIdx.x, b = blockIdx.y;
  __shared__ float L[3*60*20];                 // [row][x][c pad20], col19 = -3e38
  int ylo;
  { float yy0 = (float)(fy*8) * (59.0f/479.0f); ylo = (int)yy0; }
  for (int i = threadIdx.x; i < 3600; i += 256){
    int r = i/1200, rem = i - r*1200, x = rem/20, c = rem - x*20;
    int row = min(ylo + r, 59);
    L[i] = (c < 19) ? seg60[(((size_t)b*60 + row)*60 + x)*NCLS + c] : -3.0e38f;
  }
  __syncthreads();
  int wave = threadIdx.x >> 6, lane = threadIdx.x & 63;
  int py = fy*8 + (lane >> 3), lpx = lane & 7;
  float yy = (float)py * (59.0f/479.0f); int y0 = (int)yy; int y1 = min(y0+1, 59); float wy = yy - (float)y0;
  const float* r0 = L + (y0 - ylo)*1200;
  const float* r1 = L + (y1 - ylo)*1200;
  #pragma unroll 3
  for (int pass = 0; pass < 15; pass++){
    int fx = pass*4 + wave;                    // 0..59
    int px = fx*8 + lpx;
    float xx = (float)px * (59.0f/479.0f); int x0 = (int)xx; int x1 = min(x0+1, 59); float wx = xx - (float)x0;
    float w00 = (1.f-wy)*(1.f-wx), w01 = (1.f-wy)*wx, w10 = wy*(1.f-wx), w11 = wy*wx;
    const float* s00 = r0 + x0*20; const float* s01 = r0 + x1*20;
    const float* s10 = r1 + x0*20; const float* s11 = r1 + x1*20;
    float best = -3.0e38f; int bc = 0;
    #pragma unroll
    for (int c = 0; c < NCLS; c++){
      float v = w00*s00[c] + w01*s01[c] + w10*s10[c] + w11*s11[c];
      if (v > best){ best = v; bc = c; }       // strict > == first-occurrence argmax
    }
    int cnt = 0;
    #pragma unroll
    for (int c = 0; c < NCLS; c++){
      unsigned long long m = __ballot(bc == c);
      if (lane == c) cnt = __popcll(m);
    }
    int ky = fy/10, qy = fy - (fy/10)*10, kx = fx/10, qx = fx - (fx/10)*10;
    int q = qy*10 + qx, k = ky*6 + kx;         // wave-uniform
    if (lane < NCLS){
      unsigned short hv = f2b((float)cnt * (1.0f/64.0f));   // k/64: bf16-exact
      argxT[(size_t)(b*NCLS + lane)*7168 + q*64 + (((k>>3) ^ (q&7))<<3) + (k&7)] = hv;
    }
  }
}

// ---------------- K7v5: MFMA corr + reg h-table + fused out2 copy ----------------
__global__ __launch_bounds__(256) void k7_final(
    const float* __restrict__ att, const unsigned short* __restrict__ argxT,
    const float* __restrict__ seg60, float* __restrict__ out, float* __restrict__ out2)
{
  int pr = blockIdx.x, c = blockIdx.y, b = blockIdx.z;
  __shared__ char pool[22720];
  unsigned short* Abf = (unsigned short*)pool;            // [48][64] swz (phase A)
  unsigned short* Ubf = (unsigned short*)(pool + 6144);   // [112][64] swz (phase A)
  float* corrl = (float*)pool;                            // [48][112] (phase B, overlaps A/U)
  float* inv   = (float*)(pool + 21504);                  // [48]
  float* srow  = (float*)(pool + 21696);                  // [4][64]
  const int t = threadIdx.x;
  const int lane = t & 63;
  const int wave = t >> 6;

  int ybase; { float yy0 = (float)(pr*10)*(59.0f/479.0f); ybase = (int)yy0; }

  // ---- phase 1: stage A (att->bf16 swizzled) + write out2 copy, U via GLOAD16, srow, inv ----
  const size_t aoff = (((size_t)b*NCLS + c)*2304 + (size_t)pr*48)*36;
  const float* ab = att + aoff;
  float* o2 = out2 + aoff;
  for (int i = t; i < 768; i += 256){
    int pc = i >> 4, j = i & 15;          // j: 4-k slot (0..15), data for j<9
    ushort4 w4 = make_ushort4(0,0,0,0);
    if (j < 9){
      f4v v = *(const f4v*)(ab + pc*36 + j*4);
      *(f4v*)(o2 + pc*36 + j*4) = v;      // fused attentions -> out2 copy
      w4.x = f2b(v[0]); w4.y = f2b(v[1]); w4.z = f2b(v[2]); w4.w = f2b(v[3]);
    }
    int ch = j >> 1;
    *(ushort4*)((char*)Abf + pc*128 + (((ch ^ (pc & 7)))<<4) + (j & 1)*8) = w4;
  }
  {
    const unsigned short* up = argxT + (size_t)(b*NCLS + c)*7168;
    #pragma unroll
    for (int r = 0; r < 4; r++){
      int chunk0 = r*256 + wave*64;
      if (chunk0 < 896)                   // wave-uniform
        GLOAD16(up + (size_t)(chunk0 + lane)*8, Ubf + (size_t)chunk0*8);
    }
  }
  if (t < 240){
    int j = t/60, x = t - (t/60)*60;
    int row = min(ybase + j, 59);
    srow[j*64 + x] = seg60[(((size_t)b*60 + row)*60 + x)*NCLS + c];
  }
  if (t < 48){
    int nz = 0;
    #pragma unroll
    for (int j2 = 0; j2 < 9; j2++){
      f4v v = *(const f4v*)(ab + t*36 + j2*4);
      nz += (v[0]!=0.f)+(v[1]!=0.f)+(v[2]!=0.f)+(v[3]!=0.f);
    }
    inv[t] = 1.0f/((float)nz + 1e-5f);
  }
  __syncthreads();

  // ---- phase 2: MFMA (21 tile-pairs over 4 waves) + h-table into registers ----
  f4v acc[6];
  #pragma unroll
  for (int s = 0; s < 6; s++) acc[s] = (f4v){0.f,0.f,0.f,0.f};
  #pragma unroll
  for (int s = 0; s < 6; s++){
    int pi = wave + s*4;
    if (pi < 21){
      int M = pi/7, N = pi - (pi/7)*7;
      #pragma unroll
      for (int ks = 0; ks < 2; ks++){
        int chunk = ks*4 + (lane >> 4);
        int ar = M*16 + (lane & 15);
        s8v af = *(s8v*)((char*)Abf + ar*128 + ((chunk ^ (ar & 7))<<4));
        int qr = N*16 + (lane & 15);
        s8v bg = *(s8v*)((char*)Ubf + qr*128 + ((chunk ^ (qr & 7))<<4));
        acc[s] = __builtin_amdgcn_mfma_f32_16x16x32_bf16(af, bg, acc[s], 0, 0, 0);
      }
    }
  }
  float hA[4], hB[4];
  {
    float xxa = (float)t * (59.0f/479.0f);
    int xa0 = (int)xxa; int xa1 = min(xa0+1, 59); float wxa = xxa - (float)xa0;
    int px2 = t + 256;
    float xxb = (float)px2 * (59.0f/479.0f);
    int xb0 = (int)xxb; int xb1 = min(xb0+1, 59); float wxb = xxb - (float)xb0;
    #pragma unroll
    for (int j = 0; j < 4; j++){
      hA[j] = (1.f-wxa)*srow[j*64 + xa0] + wxa*srow[j*64 + xa1];
      hB[j] = (px2 < 480) ? ((1.f-wxb)*srow[j*64 + xb0] + wxb*srow[j*64 + xb1]) : 0.f;
    }
  }
  __syncthreads();

  // ---- phase 3: corr = acc*inv -> corrl (overwrites A/U) ----
  #pragma unroll
  for (int s = 0; s < 6; s++){
    int pi = wave + s*4;
    if (pi < 21){
      int M = pi/7, N = pi - (pi/7)*7;
      int q = N*16 + (lane & 15);
      #pragma unroll
      for (int r = 0; r < 4; r++){
        int pc = M*16 + (lane >> 4)*4 + r;
        corrl[pc*112 + q] = acc[s][r] * inv[pc];
      }
    }
  }
  __syncthreads();

  // ---- phase 4: coalesced output, h from registers (row-select is wave-uniform) ----
  float* outb = out + ((size_t)b*NCLS + c)*230400 + (size_t)pr*4800;
  int pcA = (t*6554) >> 16, qxA = t - pcA*10;
  int px2 = t + 256;
  int pcB = (px2*6554) >> 16, qxB = px2 - pcB*10;
  #pragma unroll
  for (int qy = 0; qy < 10; qy++){
    int py = pr*10 + qy;
    float yy = (float)py * (59.0f/479.0f);
    int y0 = (int)yy; int y1 = min(y0+1, 59); float wy = yy - (float)y0;
    int j0 = y0 - ybase, j1 = y1 - ybase;      // uniform across block
    float h0a = (j0==0)?hA[0]:(j0==1)?hA[1]:(j0==2)?hA[2]:hA[3];
    float h1a = (j1==0)?hA[0]:(j1==1)?hA[1]:(j1==2)?hA[2]:hA[3];
    float omw = 1.f - wy;
    float xv = omw*h0a + wy*h1a;
    outb[qy*480 + t] = xv * (1.f + corrl[pcA*112 + qy*10 + qxA]);
    if (px2 < 480){
      float h0b = (j0==0)?hB[0]:(j0==1)?hB[1]:(j0==2)?hB[2]:hB[3];
      float h1b = (j1==0)?hB[0]:(j1==1)?hB[1]:(j1==2)?hB[2]:hB[3];
      float xv2 = omw*h0b + wy*h1b;
      outb[qy*480 + px2] = xv2 * (1.f + corrl[pcB*112 + qy*10 + qxB]);
    }
  }
}

extern "C" void kernel_launch(void* const* d_in, const int* in_sizes, int n_in,
                              void* d_out, int out_size, void* d_ws, size_t ws_size,
                              hipStream_t stream)
{
  (void)in_sizes; (void)n_in; (void)out_size; (void)ws_size;
  const float* feat   = (const float*)d_in[0];
  const float* attn   = (const float*)d_in[1];
  const float* w_psp  = (const float*)d_in[2];
  const float* b_psp0 = (const float*)d_in[3];
  const float* png    = (const float*)d_in[4];
  const float* pnb    = (const float*)d_in[5];
  const float* pnm    = (const float*)d_in[6];
  const float* pnv    = (const float*)d_in[7];
  const float* wconv  = (const float*)d_in[8];
  const float* cg     = (const float*)d_in[9];
  const float* cbt    = (const float*)d_in[10];
  const float* cm     = (const float*)d_in[11];
  const float* cv     = (const float*)d_in[12];
  const float* wseg   = (const float*)d_in[13];
  const float* bseg   = (const float*)d_in[14];

  float* out1 = (float*)d_out;                       // [8,19,480,480]
  float* out2 = out1 + (size_t)35020800;             // attentions copy

  char* ws = (char*)d_ws;
  unsigned short* x512p = (unsigned short*)(ws + OFF_X512);
  float* pooled = (float*)(ws + OFF_POOL);
  unsigned short* zbufT = (unsigned short*)(ws + OFF_Z);
  float* bns    = (float*)(ws + OFF_BNS);
  float* bnb    = (float*)(ws + OFF_BNB);
  float* seg60  = (float*)(ws + OFF_SEG);
  unsigned short* argxT = (unsigned short*)(ws + OFF_ARGX);
  unsigned short* wsegT = (unsigned short*)(ws + OFF_WSEG);
  unsigned short* wfT   = (unsigned short*)(ws + OFF_WF);
  unsigned short* featT = (unsigned short*)d_out;    // scratch inside out1 (k7 overwrites)

  k_setup<<<4346, 256, 0, stream>>>(feat, featT, x512p, wseg, wsegT, wconv, wfT,
                                    cg, cbt, cm, cv, bns, bnb, argxT, zbufT, pooled);
  k2_branch<<<400, 256, 0, stream>>>(pooled, w_psp, b_psp0, png, pnb, pnm, pnv, wconv, zbufT);
  k3_gemm<<<dim3(4,29,8), 256, 0, stream>>>(featT, wfT, zbufT, bns, bnb, x512p);
  k4_conv<<<dim3(60,8), 256, 0, stream>>>(x512p, wsegT, bseg, seg60);
  k5_argmax<<<dim3(60,8), 256, 0, stream>>>(seg60, argxT);
  k7_final<<<dim3(48,19,8), 256, 0, stream>>>(attn, argxT, seg60, out1, out2);
}